// Round 4
// baseline (384.028 us; speedup 1.0000x reference)
//
#include <hip/hip_runtime.h>

typedef float f32x4 __attribute__((ext_vector_type(4)));

// ---------------------------------------------------------------------------
// k_emb_v: er[M x 64] = X[M x 1000] @ We^T + be   (used for rated only, M=1000)
// Block = 256 threads = 16 rows x 64 cols; thread (rs, n) does 4 rows.
// ---------------------------------------------------------------------------
__global__ __launch_bounds__(256) void k_emb_v(
    const float* __restrict__ X, const float* __restrict__ W, const float* __restrict__ be,
    float* __restrict__ out, int M)
{
    const int n  = threadIdx.x & 63;
    const int rs = threadIdx.x >> 6;
    const int r0 = blockIdx.x * 16 + rs * 4;

    const int ra = min(r0 + 0, M - 1);
    const int rb = min(r0 + 1, M - 1);
    const int rc = min(r0 + 2, M - 1);
    const int rd = min(r0 + 3, M - 1);
    const float* xa = X + (size_t)ra * 1000;
    const float* xb = X + (size_t)rb * 1000;
    const float* xc = X + (size_t)rc * 1000;
    const float* xd = X + (size_t)rd * 1000;
    const float* wr = W + (size_t)n * 1000;

    float acc0 = 0.f, acc1 = 0.f, acc2 = 0.f, acc3 = 0.f;
    for (int kc = 0; kc < 1000; kc += 4) {
        f32x4 w4 = *(const f32x4*)(wr + kc);
        f32x4 a4 = *(const f32x4*)(xa + kc);
        f32x4 b4 = *(const f32x4*)(xb + kc);
        f32x4 c4 = *(const f32x4*)(xc + kc);
        f32x4 d4 = *(const f32x4*)(xd + kc);
#pragma unroll
        for (int j = 0; j < 4; ++j) {
            acc0 += a4[j] * w4[j];
            acc1 += b4[j] * w4[j];
            acc2 += c4[j] * w4[j];
            acc3 += d4[j] * w4[j];
        }
    }
    const float bias = be[n];
    if (r0 + 0 < M) out[(size_t)(r0 + 0) * 64 + n] = acc0 + bias;
    if (r0 + 1 < M) out[(size_t)(r0 + 1) * 64 + n] = acc1 + bias;
    if (r0 + 2 < M) out[(size_t)(r0 + 2) * 64 + n] = acc2 + bias;
    if (r0 + 3 < M) out[(size_t)(r0 + 3) * 64 + n] = acc3 + bias;
}

// ---------------------------------------------------------------------------
// k_ar: ar[i,a] = sum_e er[i,e] * Wa1[a, 64+e]   (ba1 folded into acL in k3)
// ---------------------------------------------------------------------------
__global__ void k_ar(const float* __restrict__ er, const float* __restrict__ Wa1,
                     float* __restrict__ ar)
{
    int idx = blockIdx.x * 256 + threadIdx.x;
    if (idx >= 16000) return;
    int i = idx >> 4, a = idx & 15;
    const float* e = er + (size_t)i * 64;
    const float* w = Wa1 + a * 128 + 64;
    float acc = 0.f;
#pragma unroll
    for (int k = 0; k < 64; ++k) acc += e[k] * w[k];
    ar[idx] = acc;
}

// ---------------------------------------------------------------------------
// k3: fully fused per 8-row batch tile: e_c (in-block, LDS) -> attention
// scores -> softmax -> user_emb -> MLP. Workspace reads: er, ar only.
// LDS = 8664 floats (34.7 KB):
//   SC[1000][8] pitch 8 (transposed: phase-2 reads 8 b-weights as 2x f32x4)
//   ACL[8][17], SUMS[8], EC[8][65] (pitch 65: conflict-free column reads)
// After phase 2's reads SC is dead -> overlay UE[4][8][64], XB[8][128],
// H1[8][64], H2[8][32] (all < 8000).
// ba2 is softmax-invariant (exact cancellation) and skipped.
// ---------------------------------------------------------------------------
#define SCOF   0
#define ACLOF  8000
#define SUMSOF 8136
#define ECOF   8144
#define UEOF   0
#define XBOF   2048
#define H1OF   3072
#define H2OF   3584

__global__ __launch_bounds__(256) void k3(
    const float* __restrict__ cand, const float* __restrict__ We, const float* __restrict__ be,
    const float* __restrict__ er, const float* __restrict__ ar,
    const float* __restrict__ um, const float* __restrict__ Wa1, const float* __restrict__ ba1,
    const float* __restrict__ Wa2,
    const float* __restrict__ Wm1, const float* __restrict__ bm1,
    const float* __restrict__ Wm2, const float* __restrict__ bm2,
    const float* __restrict__ Wm3, const float* __restrict__ bm3,
    float* __restrict__ out)
{
    __shared__ float sm[8664];
    const int t  = threadIdx.x;
    const int b0 = blockIdx.x * 8;

    // P0a: EC[b][n] = be[n] + cand[b0+b] . We[n], b = wv and wv+4.
    // cand rows are wave-broadcast; We rows lane-gathered (L2-hot, seq. kc).
    {
        const int n = t & 63, wv = t >> 6;
        const float* wr = We + (size_t)n * 1000;
        const float* xa = cand + (size_t)(b0 + wv) * 1000;
        const float* xb = cand + (size_t)(b0 + wv + 4) * 1000;
        float a0 = 0.f, a1 = 0.f;
        for (int kc = 0; kc < 1000; kc += 4) {
            f32x4 w4 = *(const f32x4*)(wr + kc);
            f32x4 x0 = *(const f32x4*)(xa + kc);
            f32x4 x1 = *(const f32x4*)(xb + kc);
#pragma unroll
            for (int j = 0; j < 4; ++j) {
                a0 += x0[j] * w4[j];
                a1 += x1[j] * w4[j];
            }
        }
        const float bias = be[n];
        sm[ECOF + wv * 65 + n]       = a0 + bias;
        sm[ECOF + (wv + 4) * 65 + n] = a1 + bias;
    }
    __syncthreads();

    // P0b: ACL[b][a] = ba1[a] + sum_e EC[b][e] * Wa1[a][e]
    if (t < 128) {
        const int b = t & 7, a = t >> 3;
        float acc = ba1[a];
        const float* w = Wa1 + a * 128;
#pragma unroll 8
        for (int e = 0; e < 64; ++e) acc += sm[ECOF + b * 65 + e] * w[e];
        sm[ACLOF + b * 17 + a] = acc;
    }
    __syncthreads();

    // P1: SC[i][b] = sum_a relu(ACL[b][a] + ar[i][a]) * Wa2[a]
    {
        const int b = t & 7, c = t >> 3;        // 32 i-chunks of 32
        float acb[16], w2[16];
#pragma unroll
        for (int a = 0; a < 16; ++a) acb[a] = sm[ACLOF + b * 17 + a];
#pragma unroll
        for (int a = 0; a < 16; ++a) w2[a] = Wa2[a];
        const int ib = c * 32;
        const int ie = (ib + 32 < 1000) ? ib + 32 : 1000;
        for (int i = ib; i < ie; ++i) {
            const f32x4* a4 = (const f32x4*)(ar + (size_t)i * 16);
            float s = 0.f;
#pragma unroll
            for (int v = 0; v < 4; ++v) {
                f32x4 rv = a4[v];
                s += fmaxf(acb[4*v+0] + rv[0], 0.f) * w2[4*v+0];
                s += fmaxf(acb[4*v+1] + rv[1], 0.f) * w2[4*v+1];
                s += fmaxf(acb[4*v+2] + rv[2], 0.f) * w2[4*v+2];
                s += fmaxf(acb[4*v+3] + rv[3], 0.f) * w2[4*v+3];
            }
            sm[SCOF + i * 8 + b] = s;
        }
    }
    __syncthreads();

    // P1.5: per-b softmax over i; rewrite SC[i][b] = exp(s-m)*um[b][i]; SUMS=1/sum
    {
        const int b = t >> 5, g = t & 31;
        float m = -1e30f;
        for (int i = g; i < 1000; i += 32) m = fmaxf(m, sm[SCOF + i * 8 + b]);
#pragma unroll
        for (int k = 1; k < 32; k <<= 1) m = fmaxf(m, __shfl_xor(m, k));
        float sum = 0.f;
        const float* umr = um + (size_t)(b0 + b) * 1000;
        for (int i = g; i < 1000; i += 32) {
            float w = __expf(sm[SCOF + i * 8 + b] - m);
            sum += w;
            sm[SCOF + i * 8 + b] = w * umr[i];
        }
#pragma unroll
        for (int k = 1; k < 32; k <<= 1) sum += __shfl_xor(sum, k);
        if (g == 0) sm[SUMSOF + b] = 1.0f / sum;
    }
    __syncthreads();

    // P2: user_emb: thread (eg = t&15, ip = t>>4) covers e = eg*4..+4,
    // i-chunk ip*63..min(+63,1000). Per i: 2x f32x4 LDS (8 b-weights),
    // 1x f32x4 global er (each er element read ONCE per block), 32 FMA.
    f32x4 acc[8];
#pragma unroll
    for (int b = 0; b < 8; ++b) acc[b] = {0.f, 0.f, 0.f, 0.f};
    {
        const int eg = t & 15, ip = t >> 4;
        const int i0 = ip * 63;
        const int i1 = (i0 + 63 < 1000) ? i0 + 63 : 1000;
        for (int i = i0; i < i1; ++i) {
            f32x4 wA = *(const f32x4*)(sm + SCOF + i * 8);
            f32x4 wB = *(const f32x4*)(sm + SCOF + i * 8 + 4);
            f32x4 e4 = *(const f32x4*)(er + (size_t)i * 64 + eg * 4);
#pragma unroll
            for (int b = 0; b < 4; ++b) {
                acc[b]     += e4 * wA[b];
                acc[b + 4] += e4 * wB[b];
            }
        }
    }
    // intra-wave reduce over the 4 ip-chunks resident in this wave
#pragma unroll
    for (int b = 0; b < 8; ++b) {
#pragma unroll
        for (int j = 0; j < 4; ++j) {
            acc[b][j] += __shfl_xor(acc[b][j], 16);
            acc[b][j] += __shfl_xor(acc[b][j], 32);
        }
    }
    __syncthreads();                            // SC reads done -> overlay legal
    {
        const int eg = t & 15, wv = t >> 6;
        if ((t & 48) == 0) {                    // one writer per (wave, eg)
#pragma unroll
            for (int b = 0; b < 8; ++b)
                *(f32x4*)(sm + UEOF + wv * 512 + b * 64 + eg * 4) = acc[b];
        }
    }
    __syncthreads();

    // P2b: sum 4 wave-partials, scale by 1/sum, build x = [EC | user_emb]
    {
        for (int idx = t; idx < 512; idx += 256) {
            int b = idx >> 6, e = idx & 63;
            float v = sm[UEOF + b * 64 + e]         + sm[UEOF + 512 + b * 64 + e]
                    + sm[UEOF + 1024 + b * 64 + e]  + sm[UEOF + 1536 + b * 64 + e];
            v *= sm[SUMSOF + b];
            sm[XBOF + b * 128 + 64 + e] = v;
            sm[XBOF + b * 128 + e] = sm[ECOF + b * 65 + e];
        }
    }
    __syncthreads();

    // MLP head: 32 threads per b
    {
        const int b = t >> 5, j = t & 31;
        const float* x = sm + XBOF + b * 128;
        for (int o = j; o < 64; o += 32) {
            float a = bm1[o];
            const float* wr = Wm1 + o * 128;
#pragma unroll 8
            for (int k = 0; k < 128; ++k) a += x[k] * wr[k];
            sm[H1OF + b * 64 + o] = fmaxf(a, 0.f);
        }
        __syncthreads();
        {
            float a = bm2[j];
            const float* wr = Wm2 + j * 64;
#pragma unroll 8
            for (int k = 0; k < 64; ++k) a += sm[H1OF + b * 64 + k] * wr[k];
            sm[H2OF + b * 32 + j] = fmaxf(a, 0.f);
        }
        __syncthreads();
        float p = sm[H2OF + b * 32 + j] * Wm3[j];
#pragma unroll
        for (int kk = 1; kk < 32; kk <<= 1) p += __shfl_xor(p, kk);
        if (j == 0) out[b0 + b] = p + bm3[0];
    }
}

extern "C" void kernel_launch(void* const* d_in, const int* in_sizes, int n_in,
                              void* d_out, int out_size, void* d_ws, size_t ws_size,
                              hipStream_t stream) {
    const float* cand  = (const float*)d_in[0];   // (8192,1000) fp32
    const float* rated = (const float*)d_in[1];   // (1000,1000)
    const float* um    = (const float*)d_in[2];   // (8192,1000)
    const float* We    = (const float*)d_in[3];   // (64,1000)
    const float* be    = (const float*)d_in[4];   // (64,)
    const float* Wa1   = (const float*)d_in[5];   // (16,128)
    const float* ba1   = (const float*)d_in[6];   // (16,)
    const float* Wa2   = (const float*)d_in[7];   // (1,16)
    // d_in[8] = ba2: softmax-invariant (exact), skipped
    const float* Wm1   = (const float*)d_in[9];   // (64,128)
    const float* bm1   = (const float*)d_in[10];  // (64,)
    const float* Wm2   = (const float*)d_in[11];  // (32,64)
    const float* bm2   = (const float*)d_in[12];  // (32,)
    const float* Wm3   = (const float*)d_in[13];  // (1,32)
    const float* bm3   = (const float*)d_in[14];  // (1,)

    // workspace: er (64000 f) + ar (16000 f) = 320 KB total.
    // (round-3 used 2.42 MB incl. a 2 MB ec buffer -> suspected d_ws overrun
    //  corrupting the harness's pristine input copies; ec now computed in-block)
    float* er  = (float*)d_ws;
    float* arw = er + 64000;
    float* out = (float*)d_out;

    k_emb_v<<<dim3(63),   dim3(256), 0, stream>>>(rated, We, be, er, 1000);
    k_ar   <<<dim3(63),   dim3(256), 0, stream>>>(er, Wa1, arw);
    k3     <<<dim3(1024), dim3(256), 0, stream>>>(cand, We, be, er, arw, um,
                                                  Wa1, ba1, Wa2, Wm1, bm1,
                                                  Wm2, bm2, Wm3, bm3, out);
}

// Round 5
// 244.807 us; speedup vs baseline: 1.5687x; 1.5687x over previous
//
#include <hip/hip_runtime.h>

typedef unsigned short u16;
typedef unsigned int   u32;
typedef float f32x4  __attribute__((ext_vector_type(4)));
typedef short bf16x8 __attribute__((ext_vector_type(8)));

// ---------------------------------------------------------------------------
// split-bf16 helpers: x ~= hi + lo with both bf16 (RNE). hi*hi', hi*lo', lo*hi'
// MFMA sum gives ~2^-16 relative error — fp32-class for this problem.
// ---------------------------------------------------------------------------
__device__ __forceinline__ void split1(float x, short& h, short& l) {
    u32 u  = __float_as_uint(x);
    u32 rb = u + 0x7fffu + ((u >> 16) & 1u);
    u16 hb = (u16)(rb >> 16);
    float lf = x - __uint_as_float((u32)hb << 16);
    u32 ul = __float_as_uint(lf);
    u32 rl = ul + 0x7fffu + ((ul >> 16) & 1u);
    h = (short)hb;
    l = (short)(rl >> 16);
}

__device__ __forceinline__ void mk_frag(f32x4 a, f32x4 b, bf16x8& hi, bf16x8& lo) {
#pragma unroll
    for (int j = 0; j < 4; ++j) { short h, l; split1(a[j], h, l); hi[j] = h; lo[j] = l; }
#pragma unroll
    for (int j = 0; j < 4; ++j) { short h, l; split1(b[j], h, l); hi[4+j] = h; lo[4+j] = l; }
}

// ---------------------------------------------------------------------------
// kemb_mfma: out[M x 64](fp32) = X[M x 1000](fp32) @ W^T[64 rows x 1000] + be
// via split-bf16 MFMA (16x16x32). Block = 4 waves; wave wv owns n-tile
// [wv*16, wv*16+16); block owns rows [blockIdx*16, +16).
// A-frag: X[m = l15][k = q*8+j]; B-frag: W[n = l15][k = q*8+j];
// C/D: col = lane&15, row = q*4 + reg  (m89/m91-verified layouts).
// K = 31*32 + 8-tail (tail lives in q==0 only).
// ---------------------------------------------------------------------------
__global__ __launch_bounds__(256) void kemb_mfma(
    const float* __restrict__ X, const float* __restrict__ W, const float* __restrict__ be,
    float* __restrict__ out, int M)
{
    const int wv   = threadIdx.x >> 6;
    const int lane = threadIdx.x & 63;
    const int l15  = lane & 15;
    const int q    = lane >> 4;

    const int arow = min(blockIdx.x * 16 + l15, M - 1);
    const float* xr = X + (size_t)arow * 1000;
    const float* wr = W + (size_t)(wv * 16 + l15) * 1000;

    const float bias = be[wv * 16 + l15];
    f32x4 acc = {bias, bias, bias, bias};

    for (int kc = 0; kc < 992; kc += 32) {
        f32x4 a0 = *(const f32x4*)(xr + kc + q * 8);
        f32x4 a1 = *(const f32x4*)(xr + kc + q * 8 + 4);
        f32x4 b0 = *(const f32x4*)(wr + kc + q * 8);
        f32x4 b1 = *(const f32x4*)(wr + kc + q * 8 + 4);
        bf16x8 ah, al, bh, bl;
        mk_frag(a0, a1, ah, al);
        mk_frag(b0, b1, bh, bl);
        acc = __builtin_amdgcn_mfma_f32_16x16x32_bf16(ah, bh, acc, 0, 0, 0);
        acc = __builtin_amdgcn_mfma_f32_16x16x32_bf16(ah, bl, acc, 0, 0, 0);
        acc = __builtin_amdgcn_mfma_f32_16x16x32_bf16(al, bh, acc, 0, 0, 0);
    }
    {   // K tail 992..999: only quad 0 holds live k
        bf16x8 ah = {0,0,0,0,0,0,0,0}, al = {0,0,0,0,0,0,0,0};
        bf16x8 bh = {0,0,0,0,0,0,0,0}, bl = {0,0,0,0,0,0,0,0};
        if (q == 0) {
            f32x4 a0 = *(const f32x4*)(xr + 992);
            f32x4 a1 = *(const f32x4*)(xr + 996);
            f32x4 b0 = *(const f32x4*)(wr + 992);
            f32x4 b1 = *(const f32x4*)(wr + 996);
            mk_frag(a0, a1, ah, al);
            mk_frag(b0, b1, bh, bl);
        }
        acc = __builtin_amdgcn_mfma_f32_16x16x32_bf16(ah, bh, acc, 0, 0, 0);
        acc = __builtin_amdgcn_mfma_f32_16x16x32_bf16(ah, bl, acc, 0, 0, 0);
        acc = __builtin_amdgcn_mfma_f32_16x16x32_bf16(al, bh, acc, 0, 0, 0);
    }
#pragma unroll
    for (int r = 0; r < 4; ++r) {
        int m = blockIdx.x * 16 + q * 4 + r;
        if (m < M) out[(size_t)m * 64 + wv * 16 + l15] = acc[r];
    }
}

// ---------------------------------------------------------------------------
// k_ar: ar[i,a] = sum_e er[i,e] * Wa1[a, 64+e]
// ---------------------------------------------------------------------------
__global__ void k_ar(const float* __restrict__ er, const float* __restrict__ Wa1,
                     float* __restrict__ ar)
{
    int idx = blockIdx.x * 256 + threadIdx.x;
    if (idx >= 16000) return;
    int i = idx >> 4, a = idx & 15;
    const float* e = er + (size_t)i * 64;
    const float* w = Wa1 + a * 128 + 64;
    float acc = 0.f;
#pragma unroll
    for (int k = 0; k < 64; ++k) acc += e[k] * w[k];
    ar[idx] = acc;
}

// ---------------------------------------------------------------------------
// k3_fast: scores -> softmax -> user_emb -> MLP for 8 batch rows, with e_c
// read from the precomputed ec chunk (no in-block GEMM).
// LDS = exactly 10000 floats (40 KB -> 4 blocks/CU).
// SC[1000][10]: slots 0..7 = per-b scores, slots 8..9 = pad, overlaid with:
//   EC   (512 vals) rows 640..895   ACL (128) rows 896..959   SUMS (8) 960..963
// Pitch 10 + strided-i P1 mapping keeps bank aliasing <= ~2-way.
// After P2's SC reads: UE[0..2047], XB[4608..5631], H1[5632..6143],
// H2[6144..6399] — all rows < 640, no collision with EC/ACL/SUMS pads.
// ---------------------------------------------------------------------------
__device__ __forceinline__ int SCI (int i, int b) { return i * 10 + b; }
__device__ __forceinline__ int ECI (int k)        { return (640 + (k >> 1)) * 10 + 8 + (k & 1); }
__device__ __forceinline__ int ACLI(int k)        { return (896 + (k >> 1)) * 10 + 8 + (k & 1); }
__device__ __forceinline__ int SUMI(int b)        { return (960 + (b >> 1)) * 10 + 8 + (b & 1); }
#define UEOF2 0
#define XBOF2 4608
#define H1OF2 5632
#define H2OF2 6144

__global__ __launch_bounds__(256) void k3_fast(
    const float* __restrict__ er, const float* __restrict__ ar, const float* __restrict__ ecC,
    const float* __restrict__ um, const float* __restrict__ Wa1, const float* __restrict__ ba1,
    const float* __restrict__ Wa2,
    const float* __restrict__ Wm1, const float* __restrict__ bm1,
    const float* __restrict__ Wm2, const float* __restrict__ bm2,
    const float* __restrict__ Wm3, const float* __restrict__ bm3,
    float* __restrict__ out, int r0)
{
    __shared__ float sm[10000];
    const int t   = threadIdx.x;
    const int b0g = r0 + blockIdx.x * 8;          // global batch row base
    const int b0l = blockIdx.x * 8;               // chunk-local row base

    // EC load: 512 floats -> pad slots
    {
        int k0 = t * 2;
        sm[ECI(k0)]     = ecC[(size_t)(b0l + (k0 >> 6)) * 64 + (k0 & 63)];
        sm[ECI(k0 + 1)] = ecC[(size_t)(b0l + ((k0 + 1) >> 6)) * 64 + ((k0 + 1) & 63)];
    }
    __syncthreads();

    // P0b: ACL[b][a] = ba1[a] + sum_e EC[b][e] * W1c[a][e]
    if (t < 128) {
        const int b = t & 7, a = t >> 3;
        float acc = ba1[a];
        const float* w = Wa1 + a * 128;
#pragma unroll 8
        for (int e = 0; e < 64; ++e) acc += sm[ECI(b * 64 + e)] * w[e];
        sm[ACLI(b * 16 + a)] = acc;
    }
    __syncthreads();

    // P1: SC[i][b] = sum_a relu(ACL[b][a] + ar[i][a]) * Wa2[a]; i strided by 32
    {
        const int b = t & 7, c = t >> 3;          // c in [0,32)
        float acb[16], w2[16];
#pragma unroll
        for (int a = 0; a < 16; ++a) acb[a] = sm[ACLI(b * 16 + a)];
#pragma unroll
        for (int a = 0; a < 16; ++a) w2[a] = Wa2[a];
        for (int j = 0; j < 32; ++j) {
            int i = c + 32 * j;
            if (i >= 1000) break;
            const f32x4* a4 = (const f32x4*)(ar + (size_t)i * 16);
            float s = 0.f;
#pragma unroll
            for (int v = 0; v < 4; ++v) {
                f32x4 rv = a4[v];
                s += fmaxf(acb[4*v+0] + rv[0], 0.f) * w2[4*v+0];
                s += fmaxf(acb[4*v+1] + rv[1], 0.f) * w2[4*v+1];
                s += fmaxf(acb[4*v+2] + rv[2], 0.f) * w2[4*v+2];
                s += fmaxf(acb[4*v+3] + rv[3], 0.f) * w2[4*v+3];
            }
            sm[SCI(i, b)] = s;
        }
    }
    __syncthreads();

    // P1.5: per-b softmax over i; SC[i][b] <- exp(s-m)*um[b][i]; SUMS = 1/sum
    {
        const int b = t >> 5, g = t & 31;
        float m = -1e30f;
        for (int i = g; i < 1000; i += 32) m = fmaxf(m, sm[SCI(i, b)]);
#pragma unroll
        for (int k = 1; k < 32; k <<= 1) m = fmaxf(m, __shfl_xor(m, k));
        float sum = 0.f;
        const float* umr = um + (size_t)(b0g + b) * 1000;
        for (int i = g; i < 1000; i += 32) {
            float w = __expf(sm[SCI(i, b)] - m);
            sum += w;
            sm[SCI(i, b)] = w * umr[i];
        }
#pragma unroll
        for (int k = 1; k < 32; k <<= 1) sum += __shfl_xor(sum, k);
        if (g == 0) sm[SUMI(b)] = 1.0f / sum;
    }
    __syncthreads();

    // P2: user_emb partials: thread (eg = t&15, ip = t>>4), e = eg*4..+3,
    // i in [ip*63, min(+63,1000)). er element read once per block.
    f32x4 acc[8];
#pragma unroll
    for (int b = 0; b < 8; ++b) acc[b] = {0.f, 0.f, 0.f, 0.f};
    {
        const int eg = t & 15, ip = t >> 4;
        const int i0 = ip * 63;
        const int i1 = (i0 + 63 < 1000) ? i0 + 63 : 1000;
        for (int i = i0; i < i1; ++i) {
            float w[8];
#pragma unroll
            for (int b = 0; b < 8; ++b) w[b] = sm[SCI(i, b)];   // 16-lane broadcast
            f32x4 e4 = *(const f32x4*)(er + (size_t)i * 64 + eg * 4);
#pragma unroll
            for (int b = 0; b < 8; ++b) acc[b] += e4 * w[b];
        }
    }
    // reduce the 4 ip's resident in each wave
#pragma unroll
    for (int b = 0; b < 8; ++b) {
#pragma unroll
        for (int j = 0; j < 4; ++j) {
            acc[b][j] += __shfl_xor(acc[b][j], 16);
            acc[b][j] += __shfl_xor(acc[b][j], 32);
        }
    }
    __syncthreads();                              // SC value reads done -> overlay
    {
        const int eg = t & 15, wv = t >> 6;
        if ((t & 48) == 0) {
#pragma unroll
            for (int b = 0; b < 8; ++b)
                *(f32x4*)(sm + UEOF2 + wv * 512 + b * 64 + eg * 4) = acc[b];
        }
    }
    __syncthreads();

    // P2b: sum 4 wave-partials, scale, build x = [EC | user_emb]
    {
        for (int idx = t; idx < 512; idx += 256) {
            int b = idx >> 6, e = idx & 63;
            float v = sm[UEOF2 + b * 64 + e]        + sm[UEOF2 + 512 + b * 64 + e]
                    + sm[UEOF2 + 1024 + b * 64 + e] + sm[UEOF2 + 1536 + b * 64 + e];
            v *= sm[SUMI(b)];
            sm[XBOF2 + b * 128 + 64 + e] = v;
            sm[XBOF2 + b * 128 + e] = sm[ECI(b * 64 + e)];
        }
    }
    __syncthreads();

    // MLP head: 32 threads per b
    {
        const int b = t >> 5, j = t & 31;
        const float* x = sm + XBOF2 + b * 128;
        for (int o = j; o < 64; o += 32) {
            float a = bm1[o];
            const float* wr = Wm1 + o * 128;
#pragma unroll 8
            for (int k = 0; k < 128; ++k) a += x[k] * wr[k];
            sm[H1OF2 + b * 64 + o] = fmaxf(a, 0.f);
        }
        __syncthreads();
        {
            float a = bm2[j];
            const float* wr = Wm2 + j * 64;
#pragma unroll 8
            for (int k = 0; k < 64; ++k) a += sm[H1OF2 + b * 64 + k] * wr[k];
            sm[H2OF2 + b * 32 + j] = fmaxf(a, 0.f);
        }
        __syncthreads();
        float p = sm[H2OF2 + b * 32 + j] * Wm3[j];
#pragma unroll
        for (int kk = 1; kk < 32; kk <<= 1) p += __shfl_xor(p, kk);
        if (j == 0) out[b0g + b] = p + bm3[0];
    }
}

// ===========================================================================
// Fallback path (ws_size < 576 KB): round-4 kernels verbatim (proven PASS).
// ===========================================================================
__global__ __launch_bounds__(256) void k_emb_v(
    const float* __restrict__ X, const float* __restrict__ W, const float* __restrict__ be,
    float* __restrict__ out, int M)
{
    const int n  = threadIdx.x & 63;
    const int rs = threadIdx.x >> 6;
    const int r0 = blockIdx.x * 16 + rs * 4;

    const int ra = min(r0 + 0, M - 1);
    const int rb = min(r0 + 1, M - 1);
    const int rc = min(r0 + 2, M - 1);
    const int rd = min(r0 + 3, M - 1);
    const float* xa = X + (size_t)ra * 1000;
    const float* xb = X + (size_t)rb * 1000;
    const float* xc = X + (size_t)rc * 1000;
    const float* xd = X + (size_t)rd * 1000;
    const float* wr = W + (size_t)n * 1000;

    float acc0 = 0.f, acc1 = 0.f, acc2 = 0.f, acc3 = 0.f;
    for (int kc = 0; kc < 1000; kc += 4) {
        f32x4 w4 = *(const f32x4*)(wr + kc);
        f32x4 a4 = *(const f32x4*)(xa + kc);
        f32x4 b4 = *(const f32x4*)(xb + kc);
        f32x4 c4 = *(const f32x4*)(xc + kc);
        f32x4 d4 = *(const f32x4*)(xd + kc);
#pragma unroll
        for (int j = 0; j < 4; ++j) {
            acc0 += a4[j] * w4[j];
            acc1 += b4[j] * w4[j];
            acc2 += c4[j] * w4[j];
            acc3 += d4[j] * w4[j];
        }
    }
    const float bias = be[n];
    if (r0 + 0 < M) out[(size_t)(r0 + 0) * 64 + n] = acc0 + bias;
    if (r0 + 1 < M) out[(size_t)(r0 + 1) * 64 + n] = acc1 + bias;
    if (r0 + 2 < M) out[(size_t)(r0 + 2) * 64 + n] = acc2 + bias;
    if (r0 + 3 < M) out[(size_t)(r0 + 3) * 64 + n] = acc3 + bias;
}

#define SCOF   0
#define ACLOF  8000
#define SUMSOF 8136
#define ECOF   8144
#define UEOF   0
#define XBOF   2048
#define H1OF   3072
#define H2OF   3584

__global__ __launch_bounds__(256) void k3_fused(
    const float* __restrict__ cand, const float* __restrict__ We, const float* __restrict__ be,
    const float* __restrict__ er, const float* __restrict__ ar,
    const float* __restrict__ um, const float* __restrict__ Wa1, const float* __restrict__ ba1,
    const float* __restrict__ Wa2,
    const float* __restrict__ Wm1, const float* __restrict__ bm1,
    const float* __restrict__ Wm2, const float* __restrict__ bm2,
    const float* __restrict__ Wm3, const float* __restrict__ bm3,
    float* __restrict__ out)
{
    __shared__ float sm[8664];
    const int t  = threadIdx.x;
    const int b0 = blockIdx.x * 8;

    {
        const int n = t & 63, wv = t >> 6;
        const float* wr = We + (size_t)n * 1000;
        const float* xa = cand + (size_t)(b0 + wv) * 1000;
        const float* xb = cand + (size_t)(b0 + wv + 4) * 1000;
        float a0 = 0.f, a1 = 0.f;
        for (int kc = 0; kc < 1000; kc += 4) {
            f32x4 w4 = *(const f32x4*)(wr + kc);
            f32x4 x0 = *(const f32x4*)(xa + kc);
            f32x4 x1 = *(const f32x4*)(xb + kc);
#pragma unroll
            for (int j = 0; j < 4; ++j) {
                a0 += x0[j] * w4[j];
                a1 += x1[j] * w4[j];
            }
        }
        const float bias = be[n];
        sm[ECOF + wv * 65 + n]       = a0 + bias;
        sm[ECOF + (wv + 4) * 65 + n] = a1 + bias;
    }
    __syncthreads();

    if (t < 128) {
        const int b = t & 7, a = t >> 3;
        float acc = ba1[a];
        const float* w = Wa1 + a * 128;
#pragma unroll 8
        for (int e = 0; e < 64; ++e) acc += sm[ECOF + b * 65 + e] * w[e];
        sm[ACLOF + b * 17 + a] = acc;
    }
    __syncthreads();

    {
        const int b = t & 7, c = t >> 3;
        float acb[16], w2[16];
#pragma unroll
        for (int a = 0; a < 16; ++a) acb[a] = sm[ACLOF + b * 17 + a];
#pragma unroll
        for (int a = 0; a < 16; ++a) w2[a] = Wa2[a];
        const int ib = c * 32;
        const int ie = (ib + 32 < 1000) ? ib + 32 : 1000;
        for (int i = ib; i < ie; ++i) {
            const f32x4* a4 = (const f32x4*)(ar + (size_t)i * 16);
            float s = 0.f;
#pragma unroll
            for (int v = 0; v < 4; ++v) {
                f32x4 rv = a4[v];
                s += fmaxf(acb[4*v+0] + rv[0], 0.f) * w2[4*v+0];
                s += fmaxf(acb[4*v+1] + rv[1], 0.f) * w2[4*v+1];
                s += fmaxf(acb[4*v+2] + rv[2], 0.f) * w2[4*v+2];
                s += fmaxf(acb[4*v+3] + rv[3], 0.f) * w2[4*v+3];
            }
            sm[SCOF + i * 8 + b] = s;
        }
    }
    __syncthreads();

    {
        const int b = t >> 5, g = t & 31;
        float m = -1e30f;
        for (int i = g; i < 1000; i += 32) m = fmaxf(m, sm[SCOF + i * 8 + b]);
#pragma unroll
        for (int k = 1; k < 32; k <<= 1) m = fmaxf(m, __shfl_xor(m, k));
        float sum = 0.f;
        const float* umr = um + (size_t)(b0 + b) * 1000;
        for (int i = g; i < 1000; i += 32) {
            float w = __expf(sm[SCOF + i * 8 + b] - m);
            sum += w;
            sm[SCOF + i * 8 + b] = w * umr[i];
        }
#pragma unroll
        for (int k = 1; k < 32; k <<= 1) sum += __shfl_xor(sum, k);
        if (g == 0) sm[SUMSOF + b] = 1.0f / sum;
    }
    __syncthreads();

    f32x4 acc[8];
#pragma unroll
    for (int b = 0; b < 8; ++b) acc[b] = {0.f, 0.f, 0.f, 0.f};
    {
        const int eg = t & 15, ip = t >> 4;
        const int i0 = ip * 63;
        const int i1 = (i0 + 63 < 1000) ? i0 + 63 : 1000;
        for (int i = i0; i < i1; ++i) {
            f32x4 wA = *(const f32x4*)(sm + SCOF + i * 8);
            f32x4 wB = *(const f32x4*)(sm + SCOF + i * 8 + 4);
            f32x4 e4 = *(const f32x4*)(er + (size_t)i * 64 + eg * 4);
#pragma unroll
            for (int b = 0; b < 4; ++b) {
                acc[b]     += e4 * wA[b];
                acc[b + 4] += e4 * wB[b];
            }
        }
    }
#pragma unroll
    for (int b = 0; b < 8; ++b) {
#pragma unroll
        for (int j = 0; j < 4; ++j) {
            acc[b][j] += __shfl_xor(acc[b][j], 16);
            acc[b][j] += __shfl_xor(acc[b][j], 32);
        }
    }
    __syncthreads();
    {
        const int eg = t & 15, wv = t >> 6;
        if ((t & 48) == 0) {
#pragma unroll
            for (int b = 0; b < 8; ++b)
                *(f32x4*)(sm + UEOF + wv * 512 + b * 64 + eg * 4) = acc[b];
        }
    }
    __syncthreads();

    {
        for (int idx = t; idx < 512; idx += 256) {
            int b = idx >> 6, e = idx & 63;
            float v = sm[UEOF + b * 64 + e]        + sm[UEOF + 512 + b * 64 + e]
                    + sm[UEOF + 1024 + b * 64 + e] + sm[UEOF + 1536 + b * 64 + e];
            v *= sm[SUMSOF + b];
            sm[XBOF + b * 128 + 64 + e] = v;
            sm[XBOF + b * 128 + e] = sm[ECOF + b * 65 + e];
        }
    }
    __syncthreads();

    {
        const int b = t >> 5, j = t & 31;
        const float* x = sm + XBOF + b * 128;
        for (int o = j; o < 64; o += 32) {
            float a = bm1[o];
            const float* wr = Wm1 + o * 128;
#pragma unroll 8
            for (int k = 0; k < 128; ++k) a += x[k] * wr[k];
            sm[H1OF + b * 64 + o] = fmaxf(a, 0.f);
        }
        __syncthreads();
        {
            float a = bm2[j];
            const float* wr = Wm2 + j * 64;
#pragma unroll 8
            for (int k = 0; k < 64; ++k) a += sm[H1OF + b * 64 + k] * wr[k];
            sm[H2OF + b * 32 + j] = fmaxf(a, 0.f);
        }
        __syncthreads();
        float p = sm[H2OF + b * 32 + j] * Wm3[j];
#pragma unroll
        for (int kk = 1; kk < 32; kk <<= 1) p += __shfl_xor(p, kk);
        if (j == 0) out[b0 + b] = p + bm3[0];
    }
}

extern "C" void kernel_launch(void* const* d_in, const int* in_sizes, int n_in,
                              void* d_out, int out_size, void* d_ws, size_t ws_size,
                              hipStream_t stream) {
    const float* cand  = (const float*)d_in[0];   // (8192,1000) fp32
    const float* rated = (const float*)d_in[1];   // (1000,1000)
    const float* um    = (const float*)d_in[2];   // (8192,1000)
    const float* We    = (const float*)d_in[3];   // (64,1000)
    const float* be    = (const float*)d_in[4];   // (64,)
    const float* Wa1   = (const float*)d_in[5];   // (16,128)
    const float* ba1   = (const float*)d_in[6];   // (16,)
    const float* Wa2   = (const float*)d_in[7];   // (1,16)
    // d_in[8] = ba2: softmax-invariant (exact), skipped
    const float* Wm1   = (const float*)d_in[9];   // (64,128)
    const float* bm1   = (const float*)d_in[10];  // (64,)
    const float* Wm2   = (const float*)d_in[11];  // (32,64)
    const float* bm2   = (const float*)d_in[12];  // (32,)
    const float* Wm3   = (const float*)d_in[13];  // (1,32)
    const float* bm3   = (const float*)d_in[14];  // (1,)

    float* er  = (float*)d_ws;           // 64000 fp32
    float* arw = er + 64000;             // 16000 fp32
    float* ec  = arw + 16000;            // chunked e_c, rows_chunk*64 fp32
    float* out = (float*)d_out;

    // ws-adaptive tiering (ws_size is call-invariant -> identical work per call).
    // fixed = er+ar = 320 KB (proven safe in round 4). Round 3 proved
    // ws_size < 2.42 MB, so the 8192 tier likely never fires; kept for safety.
    const size_t fixed_b = 80000ull * 4;
    int rows_chunk = 0;
    if      (ws_size >= fixed_b + 8192ull * 64 * 4) rows_chunk = 8192;
    else if (ws_size >= fixed_b + 4096ull * 64 * 4) rows_chunk = 4096;
    else if (ws_size >= fixed_b + 2048ull * 64 * 4) rows_chunk = 2048;
    else if (ws_size >= fixed_b + 1024ull * 64 * 4) rows_chunk = 1024;

    if (rows_chunk) {
        kemb_mfma<<<dim3(63), dim3(256), 0, stream>>>(rated, We, be, er, 1000);
        k_ar     <<<dim3(63), dim3(256), 0, stream>>>(er, Wa1, arw);
        const int nc = 8192 / rows_chunk;
        for (int c = 0; c < nc; ++c) {
            const int r0 = c * rows_chunk;
            kemb_mfma<<<dim3(rows_chunk / 16), dim3(256), 0, stream>>>(
                cand + (size_t)r0 * 1000, We, be, ec, rows_chunk);
            k3_fast<<<dim3(rows_chunk / 8), dim3(256), 0, stream>>>(
                er, arw, ec, um, Wa1, ba1, Wa2, Wm1, bm1, Wm2, bm2, Wm3, bm3, out, r0);
        }
    } else {
        // round-4 fallback (proven): fused e_c in k3
        k_emb_v<<<dim3(63),   dim3(256), 0, stream>>>(rated, We, be, er, 1000);
        k_ar   <<<dim3(63),   dim3(256), 0, stream>>>(er, Wa1, arw);
        k3_fused<<<dim3(1024), dim3(256), 0, stream>>>(cand, We, be, er, arw, um,
                                                       Wa1, ba1, Wa2, Wm1, bm1,
                                                       Wm2, bm2, Wm3, bm3, out);
    }
}

// Round 6
// 244.355 us; speedup vs baseline: 1.5716x; 1.0018x over previous
//
#include <hip/hip_runtime.h>

typedef unsigned short u16;
typedef unsigned int   u32;
typedef float f32x4  __attribute__((ext_vector_type(4)));
typedef short bf16x8 __attribute__((ext_vector_type(8)));

__device__ __forceinline__ u16 f2b_rne(float x) {
    u32 u = __float_as_uint(x);
    return (u16)((u + 0x7fffu + ((u >> 16) & 1u)) >> 16);
}
__device__ __forceinline__ float b2f(u16 u) { return __uint_as_float((u32)u << 16); }
__device__ __forceinline__ void split1(float x, u16& h, u16& l) {
    h = f2b_rne(x);
    l = f2b_rne(x - b2f(h));
}
__device__ __forceinline__ void mk_frag(f32x4 a, f32x4 b, bf16x8& hi, bf16x8& lo) {
#pragma unroll
    for (int j = 0; j < 4; ++j) { u16 h, l; split1(a[j], h, l); hi[j] = (short)h; lo[j] = (short)l; }
#pragma unroll
    for (int j = 0; j < 4; ++j) { u16 h, l; split1(b[j], h, l); hi[4+j] = (short)h; lo[4+j] = (short)l; }
}

// ---------------------------------------------------------------------------
// kemb_mfma (cand): ec[M x 64](fp32) = X @ We^T + be, split-bf16 MFMA.
// Verbatim from round 5 (proven PASS @ absmax 2e-3).
// ---------------------------------------------------------------------------
__global__ __launch_bounds__(256) void kemb_mfma(
    const float* __restrict__ X, const float* __restrict__ W, const float* __restrict__ be,
    float* __restrict__ out, int M)
{
    const int wv   = threadIdx.x >> 6;
    const int lane = threadIdx.x & 63;
    const int l15  = lane & 15;
    const int q    = lane >> 4;

    const int arow = min(blockIdx.x * 16 + l15, M - 1);
    const float* xr = X + (size_t)arow * 1000;
    const float* wr = W + (size_t)(wv * 16 + l15) * 1000;

    const float bias = be[wv * 16 + l15];
    f32x4 acc = {bias, bias, bias, bias};

    for (int kc = 0; kc < 992; kc += 32) {
        f32x4 a0 = *(const f32x4*)(xr + kc + q * 8);
        f32x4 a1 = *(const f32x4*)(xr + kc + q * 8 + 4);
        f32x4 b0 = *(const f32x4*)(wr + kc + q * 8);
        f32x4 b1 = *(const f32x4*)(wr + kc + q * 8 + 4);
        bf16x8 ah, al, bh, bl;
        mk_frag(a0, a1, ah, al);
        mk_frag(b0, b1, bh, bl);
        acc = __builtin_amdgcn_mfma_f32_16x16x32_bf16(ah, bh, acc, 0, 0, 0);
        acc = __builtin_amdgcn_mfma_f32_16x16x32_bf16(ah, bl, acc, 0, 0, 0);
        acc = __builtin_amdgcn_mfma_f32_16x16x32_bf16(al, bh, acc, 0, 0, 0);
    }
    {
        bf16x8 ah = {0,0,0,0,0,0,0,0}, al = {0,0,0,0,0,0,0,0};
        bf16x8 bh = {0,0,0,0,0,0,0,0}, bl = {0,0,0,0,0,0,0,0};
        if (q == 0) {
            mk_frag(*(const f32x4*)(xr + 992), *(const f32x4*)(xr + 996), ah, al);
            mk_frag(*(const f32x4*)(wr + 992), *(const f32x4*)(wr + 996), bh, bl);
        }
        acc = __builtin_amdgcn_mfma_f32_16x16x32_bf16(ah, bh, acc, 0, 0, 0);
        acc = __builtin_amdgcn_mfma_f32_16x16x32_bf16(ah, bl, acc, 0, 0, 0);
        acc = __builtin_amdgcn_mfma_f32_16x16x32_bf16(al, bh, acc, 0, 0, 0);
    }
#pragma unroll
    for (int r = 0; r < 4; ++r) {
        int m = blockIdx.x * 16 + q * 4 + r;
        if (m < M) out[(size_t)m * 64 + wv * 16 + l15] = acc[r];
    }
}

// ---------------------------------------------------------------------------
// kemb_rated: same GEMM for rated (M=1000), but emits:
//   er_th/er_tl: e_r TRANSPOSED split-bf16 [64][1000]  (B-operand for k3's P2)
//   ar[1000][16] = er @ W1r^T via in-kernel MFMA (k_ar kernel eliminated)
// ---------------------------------------------------------------------------
__global__ __launch_bounds__(256) void kemb_rated(
    const float* __restrict__ X, const float* __restrict__ W, const float* __restrict__ be,
    const float* __restrict__ Wa1,
    u16* __restrict__ er_th, u16* __restrict__ er_tl, float* __restrict__ ar)
{
    __shared__ float smt[16 * 68];   // er tile [16 rows i][64 e], pitch 68
    const int wv   = threadIdx.x >> 6;
    const int lane = threadIdx.x & 63;
    const int l15  = lane & 15;
    const int q    = lane >> 4;
    const int i0   = blockIdx.x * 16;

    const int arow = min(i0 + l15, 999);
    const float* xr = X + (size_t)arow * 1000;
    const float* wr = W + (size_t)(wv * 16 + l15) * 1000;

    const float bias = be[wv * 16 + l15];
    f32x4 acc = {bias, bias, bias, bias};

    for (int kc = 0; kc < 992; kc += 32) {
        bf16x8 ah, al, bh, bl;
        mk_frag(*(const f32x4*)(xr + kc + q * 8), *(const f32x4*)(xr + kc + q * 8 + 4), ah, al);
        mk_frag(*(const f32x4*)(wr + kc + q * 8), *(const f32x4*)(wr + kc + q * 8 + 4), bh, bl);
        acc = __builtin_amdgcn_mfma_f32_16x16x32_bf16(ah, bh, acc, 0, 0, 0);
        acc = __builtin_amdgcn_mfma_f32_16x16x32_bf16(ah, bl, acc, 0, 0, 0);
        acc = __builtin_amdgcn_mfma_f32_16x16x32_bf16(al, bh, acc, 0, 0, 0);
    }
    {
        bf16x8 ah = {0,0,0,0,0,0,0,0}, al = {0,0,0,0,0,0,0,0};
        bf16x8 bh = {0,0,0,0,0,0,0,0}, bl = {0,0,0,0,0,0,0,0};
        if (q == 0) {
            mk_frag(*(const f32x4*)(xr + 992), *(const f32x4*)(xr + 996), ah, al);
            mk_frag(*(const f32x4*)(wr + 992), *(const f32x4*)(wr + 996), bh, bl);
        }
        acc = __builtin_amdgcn_mfma_f32_16x16x32_bf16(ah, bh, acc, 0, 0, 0);
        acc = __builtin_amdgcn_mfma_f32_16x16x32_bf16(ah, bl, acc, 0, 0, 0);
        acc = __builtin_amdgcn_mfma_f32_16x16x32_bf16(al, bh, acc, 0, 0, 0);
    }

    const int e = wv * 16 + l15;
#pragma unroll
    for (int r = 0; r < 4; ++r) {
        int i = i0 + q * 4 + r;
        smt[(q * 4 + r) * 68 + e] = acc[r];
        if (i < 1000) {
            u16 h, l; split1(acc[r], h, l);
            er_th[(size_t)e * 1000 + i] = h;
            er_tl[(size_t)e * 1000 + i] = l;
        }
    }
    __syncthreads();

    // ar MFMA: A = er tile [m=i local][k=e], B = W1r[a][e]; wave 0 only.
    if (wv == 0) {
        f32x4 a2 = {0.f, 0.f, 0.f, 0.f};
#pragma unroll
        for (int kc = 0; kc < 64; kc += 32) {
            const float* ap = smt + l15 * 68 + kc + q * 8;
            const float* bp = Wa1 + l15 * 128 + 64 + kc + q * 8;
            bf16x8 ah, al, bh, bl;
            mk_frag(*(const f32x4*)ap, *(const f32x4*)(ap + 4), ah, al);
            mk_frag(*(const f32x4*)bp, *(const f32x4*)(bp + 4), bh, bl);
            a2 = __builtin_amdgcn_mfma_f32_16x16x32_bf16(ah, bh, a2, 0, 0, 0);
            a2 = __builtin_amdgcn_mfma_f32_16x16x32_bf16(ah, bl, a2, 0, 0, 0);
            a2 = __builtin_amdgcn_mfma_f32_16x16x32_bf16(al, bh, a2, 0, 0, 0);
        }
#pragma unroll
        for (int r = 0; r < 4; ++r) {
            int i = i0 + q * 4 + r;
            if (i < 1000) ar[(size_t)i * 16 + l15] = a2[r];
        }
    }
}

// ---------------------------------------------------------------------------
// k3v6: per 8-row tile: ACL -> scores -> softmax (packs P = exp*um as split-
// bf16 pair in u32, in place) -> user_emb via MFMA (A = P from LDS, B = er_t
// split-bf16 from ws) -> MLP.
// LDS: sc[8][1004] u32 (pitch 1004: 16B-aligned rows, ~2-way banks) 32128 B
//      smf: EC[8][65] @0, ACL[8][16] @520, SUMS[8] @648  (656 f)
// After P2 reads, sc is overlaid: XB[8][128] @0, H1 @1024, H2 @1536 (floats).
// A-frag rows 8..15 mirror rows 0..7 (D rows 8..15 are discarded dupes).
// ---------------------------------------------------------------------------
__global__ __launch_bounds__(256) void k3v6(
    const float* __restrict__ ar, const float* __restrict__ ecC,
    const u16* __restrict__ er_th, const u16* __restrict__ er_tl,
    const float* __restrict__ um, const float* __restrict__ Wa1, const float* __restrict__ ba1,
    const float* __restrict__ Wa2,
    const float* __restrict__ Wm1, const float* __restrict__ bm1,
    const float* __restrict__ Wm2, const float* __restrict__ bm2,
    const float* __restrict__ Wm3, const float* __restrict__ bm3,
    float* __restrict__ out)
{
    __shared__ u32   sc[8 * 1004];
    __shared__ float smf[656];
    float* xb = (float*)sc;
    const int t  = threadIdx.x;
    const int b0 = blockIdx.x * 8;

    // EC load
    for (int idx = t; idx < 512; idx += 256)
        smf[(idx >> 6) * 65 + (idx & 63)] = ecC[(size_t)(b0 + (idx >> 6)) * 64 + (idx & 63)];
    __syncthreads();

    // ACL[b][a] = ba1[a] + EC[b] . W1c[a]
    if (t < 128) {
        const int b = t & 7, a = t >> 3;
        float acc = ba1[a];
        const float* w = Wa1 + a * 128;
#pragma unroll 8
        for (int e = 0; e < 64; ++e) acc += smf[b * 65 + e] * w[e];
        smf[520 + b * 16 + a] = acc;
    }
    __syncthreads();

    // P1: scores
    {
        const int b = t & 7, c = t >> 3;
        float acb[16], w2[16];
#pragma unroll
        for (int a = 0; a < 16; ++a) acb[a] = smf[520 + b * 16 + a];
#pragma unroll
        for (int a = 0; a < 16; ++a) w2[a] = Wa2[a];
        for (int j = 0; j < 32; ++j) {
            int i = c + 32 * j;
            if (i >= 1000) break;
            const f32x4* a4 = (const f32x4*)(ar + (size_t)i * 16);
            float s = 0.f;
#pragma unroll
            for (int v = 0; v < 4; ++v) {
                f32x4 rv = a4[v];
                s += fmaxf(acb[4*v+0] + rv[0], 0.f) * w2[4*v+0];
                s += fmaxf(acb[4*v+1] + rv[1], 0.f) * w2[4*v+1];
                s += fmaxf(acb[4*v+2] + rv[2], 0.f) * w2[4*v+2];
                s += fmaxf(acb[4*v+3] + rv[3], 0.f) * w2[4*v+3];
            }
            sc[b * 1004 + i] = __float_as_uint(s);
        }
    }
    __syncthreads();

    // softmax; pack P = exp(s-m)*um as split-bf16 (hi | lo<<16), in place
    {
        const int b = t >> 5, g = t & 31;
        float m = -1e30f;
        for (int i = g; i < 1000; i += 32) m = fmaxf(m, __uint_as_float(sc[b * 1004 + i]));
#pragma unroll
        for (int k = 1; k < 32; k <<= 1) m = fmaxf(m, __shfl_xor(m, k));
        float sum = 0.f;
        const float* umr = um + (size_t)(b0 + b) * 1000;
        for (int i = g; i < 1000; i += 32) {
            float w = __expf(__uint_as_float(sc[b * 1004 + i]) - m);
            sum += w;
            float p = w * umr[i];
            u16 h, l; split1(p, h, l);
            sc[b * 1004 + i] = (u32)h | ((u32)l << 16);
        }
#pragma unroll
        for (int k = 1; k < 32; k <<= 1) sum += __shfl_xor(sum, k);
        if (g == 0) smf[648 + b] = 1.0f / sum;
    }
    __syncthreads();

    // P2: user_emb[b][e] via MFMA. wave wv = e-tile; A = P (LDS), B = er_t (ws).
    {
        const int wv = t >> 6, lane = t & 63, l15 = lane & 15, q = lane >> 4;
        const int m8 = l15 & 7;
        const u16* bhp = er_th + (size_t)(wv * 16 + l15) * 1000;
        const u16* blp = er_tl + (size_t)(wv * 16 + l15) * 1000;
        f32x4 acc = {0.f, 0.f, 0.f, 0.f};

        for (int kc = 0; kc < 992; kc += 32) {
            const u32* ap = sc + m8 * 1004 + kc + q * 8;
            u32 pw[8];
            *(uint4*)(pw)     = *(const uint4*)(ap);
            *(uint4*)(pw + 4) = *(const uint4*)(ap + 4);
            bf16x8 ah, al;
#pragma unroll
            for (int j = 0; j < 8; ++j) {
                ah[j] = (short)(pw[j] & 0xffffu);
                al[j] = (short)(pw[j] >> 16);
            }
            bf16x8 bh = *(const bf16x8*)(bhp + kc + q * 8);
            bf16x8 bl = *(const bf16x8*)(blp + kc + q * 8);
            acc = __builtin_amdgcn_mfma_f32_16x16x32_bf16(ah, bh, acc, 0, 0, 0);
            acc = __builtin_amdgcn_mfma_f32_16x16x32_bf16(ah, bl, acc, 0, 0, 0);
            acc = __builtin_amdgcn_mfma_f32_16x16x32_bf16(al, bh, acc, 0, 0, 0);
        }
        {   // K tail 992..999 (q==0 only)
            u32 pw[8] = {0,0,0,0,0,0,0,0};
            bf16x8 bh = {0,0,0,0,0,0,0,0}, bl = {0,0,0,0,0,0,0,0};
            if (q == 0) {
                const u32* ap = sc + m8 * 1004 + 992;
                *(uint4*)(pw)     = *(const uint4*)(ap);
                *(uint4*)(pw + 4) = *(const uint4*)(ap + 4);
                bh = *(const bf16x8*)(bhp + 992);
                bl = *(const bf16x8*)(blp + 992);
            }
            bf16x8 ah, al;
#pragma unroll
            for (int j = 0; j < 8; ++j) {
                ah[j] = (short)(pw[j] & 0xffffu);
                al[j] = (short)(pw[j] >> 16);
            }
            acc = __builtin_amdgcn_mfma_f32_16x16x32_bf16(ah, bh, acc, 0, 0, 0);
            acc = __builtin_amdgcn_mfma_f32_16x16x32_bf16(ah, bl, acc, 0, 0, 0);
            acc = __builtin_amdgcn_mfma_f32_16x16x32_bf16(al, bh, acc, 0, 0, 0);
        }
        __syncthreads();                 // all waves done reading sc -> overlay
        if (q < 2) {
#pragma unroll
            for (int r = 0; r < 4; ++r) {
                int b = q * 4 + r;       // D row = q*4+r = b (rows 8..15 dropped)
                xb[b * 128 + 64 + wv * 16 + l15] = acc[r] * smf[648 + b];
            }
        }
        for (int idx = t; idx < 512; idx += 256)
            xb[(idx >> 6) * 128 + (idx & 63)] = smf[(idx >> 6) * 65 + (idx & 63)];
    }
    __syncthreads();

    // MLP head: 32 threads per b
    {
        const int b = t >> 5, j = t & 31;
        const float* x = xb + b * 128;
        for (int o = j; o < 64; o += 32) {
            float a = bm1[o];
            const float* wr = Wm1 + o * 128;
#pragma unroll 8
            for (int k = 0; k < 128; ++k) a += x[k] * wr[k];
            xb[1024 + b * 64 + o] = fmaxf(a, 0.f);
        }
        __syncthreads();
        {
            float a = bm2[j];
            const float* wr = Wm2 + j * 64;
#pragma unroll 8
            for (int k = 0; k < 64; ++k) a += xb[1024 + b * 64 + k] * wr[k];
            xb[1536 + b * 32 + j] = fmaxf(a, 0.f);
        }
        __syncthreads();
        float p = xb[1536 + b * 32 + j] * Wm3[j];
#pragma unroll
        for (int kk = 1; kk < 32; kk <<= 1) p += __shfl_xor(p, kk);
        if (j == 0) out[b0 + b] = p + bm3[0];
    }
}

extern "C" void kernel_launch(void* const* d_in, const int* in_sizes, int n_in,
                              void* d_out, int out_size, void* d_ws, size_t ws_size,
                              hipStream_t stream) {
    const float* cand  = (const float*)d_in[0];   // (8192,1000) fp32
    const float* rated = (const float*)d_in[1];   // (1000,1000)
    const float* um    = (const float*)d_in[2];   // (8192,1000)
    const float* We    = (const float*)d_in[3];   // (64,1000)
    const float* be    = (const float*)d_in[4];   // (64,)
    const float* Wa1   = (const float*)d_in[5];   // (16,128)
    const float* ba1   = (const float*)d_in[6];   // (16,)
    const float* Wa2   = (const float*)d_in[7];   // (1,16)
    // d_in[8] = ba2: softmax-invariant (exact), skipped
    const float* Wm1   = (const float*)d_in[9];   // (64,128)
    const float* bm1   = (const float*)d_in[10];  // (64,)
    const float* Wm2   = (const float*)d_in[11];  // (32,64)
    const float* bm2   = (const float*)d_in[12];  // (32,)
    const float* Wm3   = (const float*)d_in[13];  // (1,32)
    const float* bm3   = (const float*)d_in[14];  // (1,)

    // ws layout = exactly 2,417,152 B — the ceiling proven in-use by round 5.
    float* arw   = (float*)d_ws;                  // 16000 f   (64,000 B)
    float* ec    = arw + 16000;                   // 524288 f  (2,097,152 B)
    u16*   er_th = (u16*)(ec + 524288);           // 64000 u16 (128,000 B)
    u16*   er_tl = er_th + 64000;                 // 64000 u16 (128,000 B)
    float* out   = (float*)d_out;

    kemb_rated<<<dim3(63),   dim3(256), 0, stream>>>(rated, We, be, Wa1, er_th, er_tl, arw);
    kemb_mfma <<<dim3(512),  dim3(256), 0, stream>>>(cand, We, be, ec, 8192);
    k3v6      <<<dim3(1024), dim3(256), 0, stream>>>(arw, ec, er_th, er_tl, um,
                                                     Wa1, ba1, Wa2, Wm1, bm1,
                                                     Wm2, bm2, Wm3, bm3, out);
}